// Round 1
// baseline (121.391 us; speedup 1.0000x reference)
//
#include <hip/hip_runtime.h>
#include <hip/hip_bf16.h>

typedef __bf16 bf16x8 __attribute__((ext_vector_type(8)));
typedef __bf16 bf16x4 __attribute__((ext_vector_type(4)));
typedef float  f32x4  __attribute__((ext_vector_type(4)));

constexpr int Bn = 8192, Dn = 64, On = 256;

// ---- prep: x fp32 -> bf16, row-major [B][64] (B-operand fragment layout) ----
__global__ void k_xcvt(const float* __restrict__ x, __bf16* __restrict__ xb) {
    int i = blockIdx.x * blockDim.x + threadIdx.x;      // 0 .. B*D/4-1
    float4 v = ((const float4*)x)[i];
    bf16x4 r;
    r[0] = (__bf16)v.x; r[1] = (__bf16)v.y; r[2] = (__bf16)v.z; r[3] = (__bf16)v.w;
    ((bf16x4*)xb)[i] = r;
}

// ---- prep: betasT bf16 [O][e][d] (A-operand layout) + c_proj fp32 [O][64] ----
__global__ void k_prep_beta(const float* __restrict__ betas, const float* __restrict__ centers,
                            __bf16* __restrict__ bT, float* __restrict__ cproj) {
    __shared__ float s[64 * 65];                        // +1 pad: conflict-free transpose
    const int o = blockIdx.x;
    const float* bo = betas + (size_t)o * 4096;         // betas[o][d][e]
    for (int i = threadIdx.x; i < 4096; i += 256) {
        int d = i >> 6, e = i & 63;
        s[d * 65 + e] = bo[i];
    }
    __syncthreads();
    for (int i = threadIdx.x; i < 4096; i += 256) {     // i = e*64 + d
        int e = i >> 6, d = i & 63;
        bT[(size_t)o * 4096 + i] = (__bf16)s[d * 65 + e];
    }
    if (threadIdx.x < 64) {
        int e = threadIdx.x;
        float acc = 0.f;
        for (int d = 0; d < 64; ++d) acc += s[d * 65 + e] * centers[o * 64 + d];
        cproj[o * 64 + e] = acc;                        // fp32-exact center projection
    }
}

// ---- main: 1 wave = 1 o x 128 b.  C[e,b] = beta^T x^T via MFMA, then
//      quad[b] = sum_e (cproj[e] - C[e,b])^2,  out[b,o] = exp(-quad) ----
__global__ __launch_bounds__(256) void k_main(const __bf16* __restrict__ xb,
                                              const __bf16* __restrict__ bT,
                                              const float* __restrict__ cproj,
                                              float* __restrict__ out) {
    const int wave = threadIdx.x >> 6;
    const int lane = threadIdx.x & 63;
    const int col  = lane & 15;                         // N index (b) / M index (e) for A
    const int grp  = lane >> 4;                         // k-group of 8
    const int o     = blockIdx.x * 4 + wave;
    const int bbase = blockIdx.y * 128;

    // B-operand frags (x): loaded once, reused across all 4 e-tiles.
    // B[k=d][n=b]: lane holds x[bbase+n*16+col][kstep*32 + grp*8 + 0..7] -> 16B load
    const __bf16* xrow = xb + (size_t)(bbase + col) * 64 + grp * 8;
    bf16x8 bfrag[8][2];
#pragma unroll
    for (int n = 0; n < 8; ++n)
#pragma unroll
        for (int k = 0; k < 2; ++k)
            bfrag[n][k] = *(const bf16x8*)(xrow + n * 16 * 64 + k * 32);

    // A-operand (betaT): A[m=e][k=d]: lane holds bT[o][mi*16+col][kstep*32+grp*8+0..7]
    const __bf16* bTo = bT + (size_t)o * 4096 + (size_t)col * 64 + grp * 8;
    const float*  cp  = cproj + o * 64;

    float q[8] = {0.f, 0.f, 0.f, 0.f, 0.f, 0.f, 0.f, 0.f};
#pragma unroll
    for (int mi = 0; mi < 4; ++mi) {
        bf16x8 a0 = *(const bf16x8*)(bTo + mi * 16 * 64);
        bf16x8 a1 = *(const bf16x8*)(bTo + mi * 16 * 64 + 32);
        f32x4 cpv = *(const f32x4*)(cp + mi * 16 + grp * 4);   // e = mi*16 + grp*4 + r
#pragma unroll
        for (int n = 0; n < 8; ++n) {
            f32x4 acc = {0.f, 0.f, 0.f, 0.f};
            acc = __builtin_amdgcn_mfma_f32_16x16x32_bf16(a0, bfrag[n][0], acc, 0, 0, 0);
            acc = __builtin_amdgcn_mfma_f32_16x16x32_bf16(a1, bfrag[n][1], acc, 0, 0, 0);
            // C layout: col = lane&15 (b), row = grp*4 + r (e within tile)
#pragma unroll
            for (int r = 0; r < 4; ++r) {
                float t = cpv[r] - acc[r];
                q[n] = fmaf(t, t, q[n]);
            }
        }
    }
    // reduce over e lane-groups (rows live in grp 0..3): butterfly xor 16, 32
#pragma unroll
    for (int n = 0; n < 8; ++n) {
        q[n] += __shfl_xor(q[n], 16, 64);
        q[n] += __shfl_xor(q[n], 32, 64);
    }
    // store: group g writes n = g and n = g+4  (2 stores/lane, 128 b's/wave)
#pragma unroll
    for (int n = 0; n < 8; ++n) {
        if ((n & 3) == grp) {
            int b = bbase + n * 16 + col;
            out[(size_t)b * 256 + o] = __expf(-q[n]);
        }
    }
}

extern "C" void kernel_launch(void* const* d_in, const int* in_sizes, int n_in,
                              void* d_out, int out_size, void* d_ws, size_t ws_size,
                              hipStream_t stream) {
    const float* x       = (const float*)d_in[0];   // [8192,64]
    const float* centers = (const float*)d_in[1];   // [256,1,64]
    const float* betas   = (const float*)d_in[2];   // [256,64,64]
    float* out = (float*)d_out;                     // [8192,256] fp32

    char* ws = (char*)d_ws;
    __bf16* xb  = (__bf16*)ws;                      // 1 MB
    __bf16* bT  = (__bf16*)(ws + (1 << 20));        // 2 MB
    float*  cpj = (float*)(ws + 3 * (1 << 20));     // 64 KB

    k_xcvt     <<<dim3(Bn * Dn / 4 / 256), dim3(256), 0, stream>>>(x, xb);
    k_prep_beta<<<dim3(On),                dim3(256), 0, stream>>>(betas, centers, bT, cpj);
    k_main     <<<dim3(On / 4, Bn / 128),  dim3(256), 0, stream>>>(xb, bT, cpj, out);
}

// Round 2
// 90.084 us; speedup vs baseline: 1.3475x; 1.3475x over previous
//
#include <hip/hip_runtime.h>
#include <hip/hip_bf16.h>

typedef __bf16 bf16x8 __attribute__((ext_vector_type(8)));
typedef __bf16 bf16x4 __attribute__((ext_vector_type(4)));
typedef float  f32x4  __attribute__((ext_vector_type(4)));

constexpr int Bn = 8192, Dn = 64, On = 256;

// ---- prep: betasT bf16 [O][e][d] (A-operand layout) + c_proj fp32 [O][64] ----
__global__ void k_prep_beta(const float* __restrict__ betas, const float* __restrict__ centers,
                            __bf16* __restrict__ bT, float* __restrict__ cproj) {
    __shared__ float s[64 * 65];                        // +1 pad: conflict-free transpose
    const int o = blockIdx.x, tid = threadIdx.x;
    const float* bo = betas + (size_t)o * 4096;         // betas[o][d][e]
    for (int j = tid; j < 1024; j += 256) {             // float4 quads over [d][e]
        int d = j >> 4, e = (j & 15) * 4;
        float4 v = ((const float4*)bo)[j];
        s[d * 65 + e + 0] = v.x; s[d * 65 + e + 1] = v.y;
        s[d * 65 + e + 2] = v.z; s[d * 65 + e + 3] = v.w;
    }
    __syncthreads();
    for (int j = tid; j < 1024; j += 256) {             // quads over [e][d]
        int e = j >> 4, d = (j & 15) * 4;
        bf16x4 r;
        r[0] = (__bf16)s[(d + 0) * 65 + e]; r[1] = (__bf16)s[(d + 1) * 65 + e];
        r[2] = (__bf16)s[(d + 2) * 65 + e]; r[3] = (__bf16)s[(d + 3) * 65 + e];
        *(bf16x4*)(bT + (size_t)o * 4096 + e * 64 + d) = r;
    }
    if (tid < 64) {
        float acc = 0.f;
        for (int d = 0; d < 64; ++d) acc += s[d * 65 + tid] * centers[o * 64 + d];
        cproj[o * 64 + tid] = acc;                      // fp32-exact center projection
    }
}

// ---- main: block = 4 waves, 8 o's (2 per wave), 256 b. x staged in LDS (bf16,
//      144 B row stride). A-frags + cproj register-resident. Coalesced epilogue. ----
__global__ __launch_bounds__(256, 3) void k_main(const float* __restrict__ x,
                                                 const __bf16* __restrict__ bT,
                                                 const float* __restrict__ cproj,
                                                 float* __restrict__ out) {
    __shared__ __align__(16) unsigned char smem[256 * 144 + 256 * 8 * 4];
    __bf16* sX = (__bf16*)smem;                         // [256 rows][72 elems] (pad 8)
    float*  sQ = (float*)(smem + 256 * 144);            // [256][8] quad values

    const int tid  = threadIdx.x;
    const int w    = tid >> 6, lane = tid & 63;
    const int col  = lane & 15, grp = lane >> 4;
    const int ob   = blockIdx.x;                        // 8 o's per block
    const int bbase = blockIdx.y * 256;

    // stage x fp32 -> bf16 LDS (fused convert), coalesced float4 reads
#pragma unroll
    for (int it = 0; it < 16; ++it) {
        int i = it * 256 + tid;                         // quad index: 256 rows x 16 quads
        int row = i >> 4, q4 = i & 15;
        float4 v = ((const float4*)(x + (size_t)(bbase + row) * 64))[q4];
        bf16x4 r;
        r[0] = (__bf16)v.x; r[1] = (__bf16)v.y; r[2] = (__bf16)v.z; r[3] = (__bf16)v.w;
        *(bf16x4*)(sX + row * 72 + q4 * 4) = r;
    }

    // A-fragments (betaT) + cproj, register-resident for 2 o's
    const int o0 = ob * 8 + w * 2;
    bf16x8 A[2][4][2];
    f32x4  cpv[2][4];
#pragma unroll
    for (int o2 = 0; o2 < 2; ++o2) {
        const __bf16* bo = bT + (size_t)(o0 + o2) * 4096 + (size_t)col * 64 + grp * 8;
        const float*  cp = cproj + (o0 + o2) * 64 + grp * 4;
#pragma unroll
        for (int mi = 0; mi < 4; ++mi) {
            A[o2][mi][0] = *(const bf16x8*)(bo + mi * 16 * 64);
            A[o2][mi][1] = *(const bf16x8*)(bo + mi * 16 * 64 + 32);
            cpv[o2][mi]  = *(const f32x4*)(cp + mi * 16);
        }
    }
    __syncthreads();

#pragma unroll
    for (int n = 0; n < 16; ++n) {
        const __bf16* xr = sX + (n * 16 + col) * 72 + grp * 8;
        bf16x8 x0 = *(const bf16x8*)(xr);               // d = grp*8 .. +7
        bf16x8 x1 = *(const bf16x8*)(xr + 32);          // d = 32 + grp*8 .. +7
#pragma unroll
        for (int o2 = 0; o2 < 2; ++o2) {
            f32x4 qv = {0.f, 0.f, 0.f, 0.f};
#pragma unroll
            for (int mi = 0; mi < 4; ++mi) {
                f32x4 acc = {0.f, 0.f, 0.f, 0.f};
                acc = __builtin_amdgcn_mfma_f32_16x16x32_bf16(A[o2][mi][0], x0, acc, 0, 0, 0);
                acc = __builtin_amdgcn_mfma_f32_16x16x32_bf16(A[o2][mi][1], x1, acc, 0, 0, 0);
                f32x4 t = cpv[o2][mi] - acc;            // e = mi*16 + grp*4 + r
                qv += t * t;                            // packed-fp32 codegen
            }
            float qs = (qv[0] + qv[1]) + (qv[2] + qv[3]);
            qs += __shfl_xor(qs, 16, 64);               // reduce over e lane-groups
            qs += __shfl_xor(qs, 32, 64);
            if (grp == o2) sQ[(n * 16 + col) * 8 + w * 2 + o2] = qs;
        }
    }
    __syncthreads();

    // coalesced store: thread tid = local b, writes 8 consecutive o's (32 B)
    f32x4 q0 = *(const f32x4*)(sQ + tid * 8);
    f32x4 q1 = *(const f32x4*)(sQ + tid * 8 + 4);
    f32x4 r0, r1;
#pragma unroll
    for (int j = 0; j < 4; ++j) { r0[j] = __expf(-q0[j]); r1[j] = __expf(-q1[j]); }
    float* op = out + (size_t)(bbase + tid) * 256 + ob * 8;
    *(f32x4*)op       = r0;
    *(f32x4*)(op + 4) = r1;
}

extern "C" void kernel_launch(void* const* d_in, const int* in_sizes, int n_in,
                              void* d_out, int out_size, void* d_ws, size_t ws_size,
                              hipStream_t stream) {
    const float* x       = (const float*)d_in[0];   // [8192,64]
    const float* centers = (const float*)d_in[1];   // [256,1,64]
    const float* betas   = (const float*)d_in[2];   // [256,64,64]
    float* out = (float*)d_out;                     // [8192,256] fp32

    char* ws = (char*)d_ws;
    __bf16* bT  = (__bf16*)ws;                      // 2 MB
    float*  cpj = (float*)(ws + 2 * (1 << 20));     // 64 KB

    k_prep_beta<<<dim3(On),                dim3(256), 0, stream>>>(betas, centers, bT, cpj);
    k_main     <<<dim3(On / 8, Bn / 256),  dim3(256), 0, stream>>>(x, bT, cpj, out);
}